// Round 4
// baseline (323.417 us; speedup 1.0000x reference)
//
#include <hip/hip_runtime.h>
#include <hip/hip_bf16.h>

typedef __hip_bfloat16 bf16;
typedef __attribute__((ext_vector_type(8))) __bf16 bf16x8;
typedef __attribute__((ext_vector_type(4))) float f32x4;

#define BB 8
#define NN 8192
#define DIM 256
#define HEAD 4
#define HD 64
#define RANK 64
#define BN (BB*NN)

__device__ __forceinline__ float b2f(bf16 v){ return __bfloat162float(v); }
__device__ __forceinline__ bf16 f2b(float v){ return __float2bfloat16(v); }
__device__ __forceinline__ unsigned short f2bu(float f){
    bf16 h = __float2bfloat16(f);
    return *(unsigned short*)&h;
}
__device__ __forceinline__ float u2f(unsigned short u){
    unsigned int x = ((unsigned int)u) << 16; return __uint_as_float(x);
}
__device__ __forceinline__ __bf16 f2bb(float f){
    bf16 h = __float2bfloat16(f);
    return *reinterpret_cast<__bf16*>(&h);
}
// physical position of (outer, k) in a chunk-swizzled [outer][K] bf16 LDS tile
__device__ __forceinline__ int swz(int k, int outer){
    return (((k >> 3) ^ (outer & 7)) << 3) | (k & 7);
}

// ---------------------------------------------------------------------------
// kW: precompute WattnT[c][f] (K folded, /8 folded), WvT[c][f], battn[c].
// ---------------------------------------------------------------------------
__global__ void __launch_bounds__(256) kW(
    const float* __restrict__ Wq, const float* __restrict__ bq,
    const float* __restrict__ Km, const float* __restrict__ Wv,
    unsigned short* __restrict__ WattnT, unsigned short* __restrict__ WvT,
    float* __restrict__ battn)
{
    const int c = blockIdx.x;       // output col = h*64+r
    const int h = c >> 6, r = c & 63;
    const int t = threadIdx.x;      // f
    __shared__ float Ks[64];
    if(t < 64) Ks[t] = Km[((size_t)r*HEAD + h)*64 + t];
    __syncthreads();

    const float* wqrow = Wq + (size_t)t*DIM + h*64;
    float a = 0.f;
    #pragma unroll
    for(int d = 0; d < 64; d++) a = fmaf(wqrow[d], Ks[d], a);
    WattnT[(size_t)c*DIM + t] = f2bu(0.125f * a);
    WvT[(size_t)c*DIM + t]    = f2bu(Wv[(size_t)t*DIM + c]);
    if(t == 0){
        float bb = 0.f;
        for(int d = 0; d < 64; d++) bb += bq[h*64+d]*Ks[d];
        battn[c] = 0.125f * bb;
    }
}

// ---------------------------------------------------------------------------
// kF: fused per-64-row-block pipeline:
//   GEMM1 attn = z @ WattnT^T + battn  (software-pipelined, dbuf LDS for A,
//         W b-frags direct from global/L2, one barrier per K-step)
//     epi1: in-register r-softmax (16-lane shfl butterflies), attn bf16
//           store, per-block col stats Pm/Ps, s1 -> swizzled LDS s1T[c][n]
//   GEMM2 xv = x @ WvT^T + bv   (same registers/LDS reused)
//     epi2: xv fp32 store, xv -> swizzled LDS xvT[c][n]
//   pooled: per wave w (= head w): pooled[d][r] += xvT . s1T (K = 64 rows),
//           atomicAdd into pooledT.
//   Replaces kA2-xv + kA2-attn + kD (saves kD's 96 MB re-read).
// ---------------------------------------------------------------------------
__global__ void __launch_bounds__(256) kF(
    const float* __restrict__ x, const float* __restrict__ z,
    const unsigned short* __restrict__ WattnT, const unsigned short* __restrict__ WvT,
    const float* __restrict__ battn, const float* __restrict__ bv,
    float* __restrict__ xvF, unsigned short* __restrict__ attn,
    float* __restrict__ Pm, float* __restrict__ Ps,
    float* __restrict__ pooledT)
{
    __shared__ __attribute__((aligned(16))) __bf16 As[2][64][40];   // dbuf, pad 40
    __shared__ unsigned short s1T[256*64];  // [c][n] swizzled: softmax_r weights
    __shared__ unsigned short xvT[256*64];  // [c][n] swizzled: xv bf16

    const int t    = threadIdx.x;
    const int lane = t & 63;
    const int w    = t >> 6;
    const int q    = lane >> 4;
    const int l15  = lane & 15;
    const int brow = blockIdx.x * 64;
    const int arow = t >> 2, aseg = t & 3;

    f32x4 acc[4][4];

    // ---- software-pipelined 64x256x256 GEMM into acc (same as verified kA2)
    auto runGemm = [&](const float* __restrict__ Am, const unsigned short* __restrict__ WTm){
        #pragma unroll
        for(int tm = 0; tm < 4; tm++)
            #pragma unroll
            for(int tn = 0; tn < 4; tn++) acc[tm][tn] = (f32x4){0.f,0.f,0.f,0.f};

        const float* aSrc = Am + (size_t)(brow + arow)*DIM + aseg*8;
        const unsigned short* bBase = WTm + (size_t)(w*64 + l15)*DIM + q*8;

        {
            float4 v0 = *(const float4*)(aSrc + 0);
            float4 v1 = *(const float4*)(aSrc + 4);
            __attribute__((aligned(16))) __bf16 tmp[8] = {
                f2bb(v0.x), f2bb(v0.y), f2bb(v0.z), f2bb(v0.w),
                f2bb(v1.x), f2bb(v1.y), f2bb(v1.z), f2bb(v1.w)};
            *(bf16x8*)&As[0][arow][aseg*8] = *(bf16x8*)tmp;
        }
        float4 s0 = *(const float4*)(aSrc + 32);   // slab 1, in flight
        float4 s1 = *(const float4*)(aSrc + 36);
        bf16x8 bcur[4];
        #pragma unroll
        for(int tn = 0; tn < 4; tn++)
            bcur[tn] = *(const bf16x8*)(bBase + (size_t)tn*16*DIM);
        __syncthreads();

        #pragma unroll
        for(int step = 0; step < 8; step++){
            const int cur = step & 1;
            const int k0  = step * 32;

            bf16x8 bnext[4];
            if(step < 7){
                #pragma unroll
                for(int tn = 0; tn < 4; tn++)
                    bnext[tn] = *(const bf16x8*)(bBase + (size_t)tn*16*DIM + k0 + 32);
            }

            bf16x8 af[4];
            #pragma unroll
            for(int tm = 0; tm < 4; tm++) af[tm] = *(const bf16x8*)&As[cur][tm*16 + l15][q*8];
            #pragma unroll
            for(int tm = 0; tm < 4; tm++)
                #pragma unroll
                for(int tn = 0; tn < 4; tn++)
                    acc[tm][tn] = __builtin_amdgcn_mfma_f32_16x16x32_bf16(
                        af[tm], bcur[tn], acc[tm][tn], 0, 0, 0);

            if(step < 7){
                __attribute__((aligned(16))) __bf16 tmp[8] = {
                    f2bb(s0.x), f2bb(s0.y), f2bb(s0.z), f2bb(s0.w),
                    f2bb(s1.x), f2bb(s1.y), f2bb(s1.z), f2bb(s1.w)};
                *(bf16x8*)&As[cur^1][arow][aseg*8] = *(bf16x8*)tmp;
            }
            if(step < 6){
                s0 = *(const float4*)(aSrc + (step+2)*32 + 0);
                s1 = *(const float4*)(aSrc + (step+2)*32 + 4);
            }
            #pragma unroll
            for(int tn = 0; tn < 4; tn++) bcur[tn] = bnext[tn];
            __syncthreads();
        }
    };

    const int b  = brow >> 13;
    const int nb = brow & 8191;

    // ================= GEMM 1: attn logits =================
    runGemm(z, WattnT);

    // ---- epi1: r-softmax + attn store + col stats + s1T staging ----
    {
        const size_t blk = blockIdx.x;
        float bc[4];
        #pragma unroll
        for(int tn = 0; tn < 4; tn++) bc[tn] = battn[w*64 + tn*16 + l15];

        // per-row (n) max & sum over r: local over tn, then 16-lane butterfly
        float rmax[4][4], rinv[4][4];
        #pragma unroll
        for(int tm = 0; tm < 4; tm++){
            #pragma unroll
            for(int reg = 0; reg < 4; reg++){
                float m = acc[tm][0][reg] + bc[0];
                #pragma unroll
                for(int tn = 1; tn < 4; tn++) m = fmaxf(m, acc[tm][tn][reg] + bc[tn]);
                #pragma unroll
                for(int off = 1; off < 16; off <<= 1) m = fmaxf(m, __shfl_xor(m, off, 64));
                float s = 0.f;
                #pragma unroll
                for(int tn = 0; tn < 4; tn++) s += __expf(acc[tm][tn][reg] + bc[tn] - m);
                #pragma unroll
                for(int off = 1; off < 16; off <<= 1) s += __shfl_xor(s, off, 64);
                rmax[tm][reg] = m;
                rinv[tm][reg] = 1.f / s;
            }
        }

        #pragma unroll
        for(int tn = 0; tn < 4; tn++){
            const int col = w*64 + tn*16 + l15;
            const int rr  = tn*16 + l15;
            float rv[16];
            float m16 = -1e30f;
            #pragma unroll
            for(int tm = 0; tm < 4; tm++){
                #pragma unroll
                for(int reg = 0; reg < 4; reg++){
                    float v = acc[tm][tn][reg] + bc[tn];
                    unsigned short ub = f2bu(v);
                    int n = tm*16 + q*4 + reg;
                    attn[(((size_t)(b*HEAD + w))*NN + (nb + n))*64 + rr] = ub;
                    float vr = u2f(ub);
                    rv[tm*4+reg] = vr;
                    m16 = fmaxf(m16, vr);
                    float e = __expf(v - rmax[tm][reg]) * rinv[tm][reg];
                    s1T[col*64 + ((((n>>3) ^ (col&7))<<3) | (n&7))] = f2bu(e);
                }
            }
            float s16 = 0.f;
            #pragma unroll
            for(int i = 0; i < 16; i++) s16 += __expf(rv[i] - m16);
            #pragma unroll
            for(int off = 16; off <= 32; off <<= 1){
                float m2 = __shfl_xor(m16, off, 64);
                float s2 = __shfl_xor(s16, off, 64);
                float nm = fmaxf(m16, m2);
                s16 = s16*__expf(m16-nm) + s2*__expf(m2-nm);
                m16 = nm;
            }
            if(q == 0){
                Pm[blk*256 + col] = m16;
                Ps[blk*256 + col] = s16;
            }
        }
    }

    // ================= GEMM 2: xv =================
    runGemm(x, WvT);

    // ---- epi2: xv fp32 store + xvT staging ----
    {
        float bc[4];
        #pragma unroll
        for(int tn = 0; tn < 4; tn++) bc[tn] = bv[w*64 + tn*16 + l15];
        #pragma unroll
        for(int tn = 0; tn < 4; tn++){
            const int col = w*64 + tn*16 + l15;
            #pragma unroll
            for(int tm = 0; tm < 4; tm++){
                #pragma unroll
                for(int reg = 0; reg < 4; reg++){
                    float v = acc[tm][tn][reg] + bc[tn];
                    int n = tm*16 + q*4 + reg;
                    xvF[(size_t)(brow + n)*256 + col] = v;
                    xvT[col*64 + ((((n>>3) ^ (col&7))<<3) | (n&7))] = f2bu(v);
                }
            }
        }
    }
    __syncthreads();

    // ---- pooled partial: wave w handles head w; pooled[d][r] over K=64 rows
    {
        f32x4 acc2[4][4];
        #pragma unroll
        for(int am = 0; am < 4; am++)
            #pragma unroll
            for(int ar = 0; ar < 4; ar++) acc2[am][ar] = (f32x4){0.f,0.f,0.f,0.f};

        #pragma unroll
        for(int ks = 0; ks < 2; ks++){
            const int c2 = ks*4 + q;
            bf16x8 afr[4], bfr[4];
            #pragma unroll
            for(int i = 0; i < 4; i++){
                int row = w*64 + i*16 + l15;
                int off = row*64 + ((c2 ^ (row&7))<<3);
                afr[i] = *(const bf16x8*)&xvT[off];
                bfr[i] = *(const bf16x8*)&s1T[off];
            }
            #pragma unroll
            for(int am = 0; am < 4; am++)
                #pragma unroll
                for(int ar = 0; ar < 4; ar++)
                    acc2[am][ar] = __builtin_amdgcn_mfma_f32_16x16x32_bf16(
                        afr[am], bfr[ar], acc2[am][ar], 0, 0, 0);
        }

        float* pbase = pooledT + ((size_t)(b*HEAD + w))*64*64;
        #pragma unroll
        for(int am = 0; am < 4; am++){
            #pragma unroll
            for(int ar = 0; ar < 4; ar++){
                #pragma unroll
                for(int reg = 0; reg < 4; reg++){
                    int d = am*16 + q*4 + reg;
                    int r = ar*16 + l15;
                    atomicAdd(&pbase[d*64 + r], acc2[am][ar][reg]);
                }
            }
        }
    }
}

// ---------------------------------------------------------------------------
// kC: merge per-block stats -> M,S per (b, col). grid 8 x 256.
// ---------------------------------------------------------------------------
__global__ void __launch_bounds__(256) kC(const float* __restrict__ Pm, const float* __restrict__ Ps,
                                          float* __restrict__ M, float* __restrict__ S)
{
    const int b = blockIdx.x, col = threadIdx.x;
    float m = -1e30f;
    for(int c = 0; c < 128; c++)
        m = fmaxf(m, Pm[(size_t)(b*128 + c)*256 + col]);
    float s = 0.f;
    for(int c = 0; c < 128; c++){
        size_t i = (size_t)(b*128 + c)*256 + col;
        s += Ps[i] * __expf(Pm[i] - m);
    }
    M[b*256 + col] = m;
    S[b*256 + col] = s;
}

// ---------------------------------------------------------------------------
// kE: per block (bh, 256-row chunk): thread owns a row; s2 from M/S (LDS
//   broadcast); MFMA v = s2t @ pooledT; out = sa*xv + sb*v. grid (32, 32).
// ---------------------------------------------------------------------------
__global__ void __launch_bounds__(256) kE(const unsigned short* __restrict__ attn,
                                          const float* __restrict__ xvin,
                                          const float* __restrict__ pooledT,
                                          const float* __restrict__ Mst, const float* __restrict__ Sst,
                                          const float* __restrict__ alpha, const float* __restrict__ beta,
                                          float* __restrict__ out)
{
    __shared__ unsigned short s2t[256*64];  // [row][r] swizzled
    __shared__ unsigned short plT[64*64];   // [d][r] swizzled
    __shared__ float Ms[64], Sinv[64];

    const int t = threadIdx.x, lane = t & 63, w = t >> 6;
    const int bh = blockIdx.x, chunk = blockIdx.y;
    const int b = bh >> 2, h = bh & 3;
    const int n0 = chunk * 256;
    const int row = t;

    if(t < 64){
        Ms[t]   = Mst[b*256 + h*64 + t];
        Sinv[t] = 1.f / Sst[b*256 + h*64 + t];
    }
    // stage pooledT -> bf16 LDS [d][r]
    {
        int d = t >> 2, seg = t & 3;
        const float4* pp = (const float4*)(pooledT + ((size_t)bh*64 + d)*64 + seg*16);
        float4 p0 = pp[0], p1 = pp[1], p2 = pp[2], p3 = pp[3];
        __attribute__((aligned(16))) unsigned short tmp[16] = {
            f2bu(p0.x),f2bu(p0.y),f2bu(p0.z),f2bu(p0.w),
            f2bu(p1.x),f2bu(p1.y),f2bu(p1.z),f2bu(p1.w),
            f2bu(p2.x),f2bu(p2.y),f2bu(p2.z),f2bu(p2.w),
            f2bu(p3.x),f2bu(p3.y),f2bu(p3.z),f2bu(p3.w)};
        int c0 = seg*2;
        *(uint4*)&plT[d*64 + (((c0+0) ^ (d&7))<<3)] = *(uint4*)&tmp[0];
        *(uint4*)&plT[d*64 + (((c0+1) ^ (d&7))<<3)] = *(uint4*)&tmp[8];
    }
    __syncthreads();

    // ---- phase 1: s2 rows ----
    {
        const uint4* ap = (const uint4*)(attn + ((size_t)bh*NN + n0 + row)*64);
        #pragma unroll
        for(int c = 0; c < 8; c++){
            uint4 u = ap[c];
            unsigned int uu[4] = {u.x, u.y, u.z, u.w};
            unsigned int ov[4];
            #pragma unroll
            for(int p = 0; p < 4; p++){
                int r = c*8 + p*2;
                float v0 = __uint_as_float(uu[p] << 16);
                float v1 = __uint_as_float(uu[p] & 0xffff0000u);
                float e0 = __expf(v0 - Ms[r])   * Sinv[r];
                float e1 = __expf(v1 - Ms[r+1]) * Sinv[r+1];
                ov[p] = (unsigned int)f2bu(e0) | ((unsigned int)f2bu(e1) << 16);
            }
            uint4 w4; w4.x = ov[0]; w4.y = ov[1]; w4.z = ov[2]; w4.w = ov[3];
            *(uint4*)&s2t[row*64 + ((c ^ (row&7))<<3)] = w4;
        }
    }
    __syncthreads();

    // ---- phase 2: MFMA v[row][d] = sum_r s2t . plT ----
    const int q = lane >> 4, l15 = lane & 15;
    f32x4 acc[4][4];
    #pragma unroll
    for(int tm = 0; tm < 4; tm++)
        #pragma unroll
        for(int tn = 0; tn < 4; tn++) acc[tm][tn] = (f32x4){0.f,0.f,0.f,0.f};

    #pragma unroll
    for(int s = 0; s < 2; s++){
        int c = s*4 + q;
        bf16x8 bfr[4], af[4];
        #pragma unroll
        for(int tn = 0; tn < 4; tn++){
            int dn = tn*16 + l15;
            bfr[tn] = *(const bf16x8*)&plT[dn*64 + ((c ^ (dn&7))<<3)];
        }
        #pragma unroll
        for(int tm = 0; tm < 4; tm++){
            int ra = w*64 + tm*16 + l15;
            af[tm] = *(const bf16x8*)&s2t[ra*64 + ((c ^ (ra&7))<<3)];
        }
        #pragma unroll
        for(int tm = 0; tm < 4; tm++)
            #pragma unroll
            for(int tn = 0; tn < 4; tn++)
                acc[tm][tn] = __builtin_amdgcn_mfma_f32_16x16x32_bf16(
                    af[tm], bfr[tn], acc[tm][tn], 0, 0, 0);
    }

    const float sa = 1.f / (1.f + __expf(-alpha[h]));
    const float sb = 1.f / (1.f + __expf(-beta[h]));
    #pragma unroll
    for(int tm = 0; tm < 4; tm++){
        #pragma unroll
        for(int reg = 0; reg < 4; reg++){
            int rowo = w*64 + tm*16 + q*4 + reg;
            size_t gbase = ((size_t)(b*NN + n0 + rowo))*256 + h*64;
            #pragma unroll
            for(int tn = 0; tn < 4; tn++){
                int d = tn*16 + l15;
                out[gbase + d] = sa*xvin[gbase + d] + sb*acc[tm][tn][reg];
            }
        }
    }
}

extern "C" void kernel_launch(void* const* d_in, const int* in_sizes, int n_in,
                              void* d_out, int out_size, void* d_ws, size_t ws_size,
                              hipStream_t stream)
{
    (void)in_sizes; (void)n_in; (void)out_size; (void)ws_size;
    const float* x     = (const float*)d_in[0];
    const float* z     = (const float*)d_in[1];
    const float* Wq    = (const float*)d_in[2];
    const float* bq    = (const float*)d_in[3];
    const float* Km    = (const float*)d_in[4];
    const float* Wv    = (const float*)d_in[5];
    const float* bv    = (const float*)d_in[6];
    const float* alpha = (const float*)d_in[7];
    const float* beta  = (const float*)d_in[8];
    float* out = (float*)d_out;

    // xv fp32 lives in d_out: kF writes, kE reads, kE overwrites out[i]
    // in the same thread that read xv[i].
    float* xv = out;

    char* ws = (char*)d_ws;
    unsigned short* attn  = (unsigned short*)(ws + 0);         // 33,554,432 B  [b][h][n][r]
    float* pooledT = (float*)(ws + 33554432);                  // 524,288 B    [bh][d][r]
    float* Mst     = (float*)(ws + 34078720);                  // 8,192 B      [b][col]
    float* Sst     = (float*)(ws + 34086912);                  // 8,192 B
    float* Pm      = (float*)(ws + 34095104);                  // 1,048,576 B  [1024][256]
    float* Ps      = (float*)(ws + 35143680);                  // 1,048,576 B
    unsigned short* WattnT = (unsigned short*)(ws + 36192256); // 131,072 B
    unsigned short* WvT    = (unsigned short*)(ws + 36323328); // 131,072 B
    float* battn   = (float*)(ws + 36454400);                  // 1,024 B
                                                               // total: 36,455,424 B

    (void)hipMemsetAsync(pooledT, 0, 524288, stream);
    kW<<<dim3(256), 256, 0, stream>>>(Wq, bq, Km, Wv, WattnT, WvT, battn);
    kF<<<dim3(BN/64), 256, 0, stream>>>(x, z, WattnT, WvT, battn, bv, xv, attn, Pm, Ps, pooledT);
    kC<<<dim3(8), 256, 0, stream>>>(Pm, Ps, Mst, Sst);
    kE<<<dim3(32, 32), 256, 0, stream>>>(attn, xv, pooledT, Mst, Sst, alpha, beta, out);
}

// Round 5
// 298.971 us; speedup vs baseline: 1.0818x; 1.0818x over previous
//
#include <hip/hip_runtime.h>
#include <hip/hip_bf16.h>

typedef __hip_bfloat16 bf16;
typedef __attribute__((ext_vector_type(8))) __bf16 bf16x8;
typedef __attribute__((ext_vector_type(4))) float f32x4;

#define BB 8
#define NN 8192
#define DIM 256
#define HEAD 4
#define HD 64
#define RANK 64
#define BN (BB*NN)

__device__ __forceinline__ float b2f(bf16 v){ return __bfloat162float(v); }
__device__ __forceinline__ bf16 f2b(float v){ return __float2bfloat16(v); }
__device__ __forceinline__ unsigned short f2bu(float f){
    bf16 h = __float2bfloat16(f);
    return *(unsigned short*)&h;
}
__device__ __forceinline__ float u2f(unsigned short u){
    unsigned int x = ((unsigned int)u) << 16; return __uint_as_float(x);
}
__device__ __forceinline__ __bf16 f2bb(float f){
    bf16 h = __float2bfloat16(f);
    return *reinterpret_cast<__bf16*>(&h);
}
// physical position of (outer, k) in a chunk-swizzled [outer][K] bf16 LDS tile
__device__ __forceinline__ int swz(int k, int outer){
    return (((k >> 3) ^ (outer & 7)) << 3) | (k & 7);
}

// ---------------------------------------------------------------------------
// kW: precompute WattnT[c][f] (K folded, /8 folded), WvT[c][f], battn[c].
// ---------------------------------------------------------------------------
__global__ void __launch_bounds__(256) kW(
    const float* __restrict__ Wq, const float* __restrict__ bq,
    const float* __restrict__ Km, const float* __restrict__ Wv,
    unsigned short* __restrict__ WattnT, unsigned short* __restrict__ WvT,
    float* __restrict__ battn)
{
    const int c = blockIdx.x;       // output col = h*64+r
    const int h = c >> 6, r = c & 63;
    const int t = threadIdx.x;      // f
    __shared__ float Ks[64];
    if(t < 64) Ks[t] = Km[((size_t)r*HEAD + h)*64 + t];
    __syncthreads();

    const float* wqrow = Wq + (size_t)t*DIM + h*64;
    float a = 0.f;
    #pragma unroll
    for(int d = 0; d < 64; d++) a = fmaf(wqrow[d], Ks[d], a);
    WattnT[(size_t)c*DIM + t] = f2bu(0.125f * a);
    WvT[(size_t)c*DIM + t]    = f2bu(Wv[(size_t)t*DIM + c]);
    if(t == 0){
        float bb = 0.f;
        for(int d = 0; d < 64; d++) bb += bq[h*64+d]*Ks[d];
        battn[c] = 0.125f * bb;
    }
}

// ---------------------------------------------------------------------------
// kG: merged GEMM dispatch, 2048 blocks. role = blockIdx.x & 1:
//   role 0: xv  = x @ WvT^T + bv      -> fp32 outF
//   role 1: attn = z @ WattnT^T + battn -> bf16 attn + col stats Pm/Ps
// Body identical to the verified r3 kA2 (software-pipelined dbuf LDS for A,
// W b-frags direct from L2, one barrier per K-step). Interleaved roles put
// read-dominant and write-dominant blocks on the machine simultaneously.
// ---------------------------------------------------------------------------
__global__ void __launch_bounds__(256) kG(
    const float* __restrict__ x, const float* __restrict__ z,
    const unsigned short* __restrict__ WvT, const unsigned short* __restrict__ WattnT,
    const float* __restrict__ bv, const float* __restrict__ battn,
    float* __restrict__ outF, unsigned short* __restrict__ outB,
    float* __restrict__ Pm, float* __restrict__ Ps)
{
    __shared__ __attribute__((aligned(16))) __bf16 As[2][64][40];  // dbuf, pad 40

    const int role = blockIdx.x & 1;
    const int tile = blockIdx.x >> 1;

    const float* A            = role ? z : x;
    const unsigned short* WT  = role ? WattnT : WvT;
    const float* bias         = role ? battn : bv;

    const int t    = threadIdx.x;
    const int lane = t & 63;
    const int w    = t >> 6;
    const int q    = lane >> 4;
    const int l15  = lane & 15;
    const int brow = tile * 64;

    f32x4 acc[4][4];
    #pragma unroll
    for(int tm = 0; tm < 4; tm++)
        #pragma unroll
        for(int tn = 0; tn < 4; tn++) acc[tm][tn] = (f32x4){0.f,0.f,0.f,0.f};

    const int arow = t >> 2, aseg = t & 3;
    const float* aSrc = A + (size_t)(brow + arow)*DIM + aseg*8;
    //   b-frag col = w*64 + tn*16 + l15, k = k0 + q*8 .. +8   (bf16 in WT)
    const unsigned short* bBase = WT + (size_t)(w*64 + l15)*DIM + q*8;

    // ---- prologue: slab 0 -> LDS buf0; issue slab-1 loads; W step-0 frags
    {
        float4 v0 = *(const float4*)(aSrc + 0);
        float4 v1 = *(const float4*)(aSrc + 4);
        __attribute__((aligned(16))) __bf16 tmp[8] = {
            f2bb(v0.x), f2bb(v0.y), f2bb(v0.z), f2bb(v0.w),
            f2bb(v1.x), f2bb(v1.y), f2bb(v1.z), f2bb(v1.w)};
        *(bf16x8*)&As[0][arow][aseg*8] = *(bf16x8*)tmp;
    }
    float4 s0 = *(const float4*)(aSrc + 32);   // slab 1, in flight
    float4 s1 = *(const float4*)(aSrc + 36);
    bf16x8 bcur[4];
    #pragma unroll
    for(int tn = 0; tn < 4; tn++)
        bcur[tn] = *(const bf16x8*)(bBase + (size_t)tn*16*DIM);
    __syncthreads();

    #pragma unroll
    for(int step = 0; step < 8; step++){
        const int cur = step & 1;
        const int k0  = step * 32;

        // prefetch W fragments for next step (L2-resident)
        bf16x8 bnext[4];
        if(step < 7){
            #pragma unroll
            for(int tn = 0; tn < 4; tn++)
                bnext[tn] = *(const bf16x8*)(bBase + (size_t)tn*16*DIM + k0 + 32);
        }

        // compute on current buffer
        bf16x8 af[4];
        #pragma unroll
        for(int tm = 0; tm < 4; tm++) af[tm] = *(const bf16x8*)&As[cur][tm*16 + l15][q*8];
        #pragma unroll
        for(int tm = 0; tm < 4; tm++)
            #pragma unroll
            for(int tn = 0; tn < 4; tn++)
                acc[tm][tn] = __builtin_amdgcn_mfma_f32_16x16x32_bf16(
                    af[tm], bcur[tn], acc[tm][tn], 0, 0, 0);

        // stage slab step+1 (loaded one step ago) into the other buffer
        if(step < 7){
            __attribute__((aligned(16))) __bf16 tmp[8] = {
                f2bb(s0.x), f2bb(s0.y), f2bb(s0.z), f2bb(s0.w),
                f2bb(s1.x), f2bb(s1.y), f2bb(s1.z), f2bb(s1.w)};
            *(bf16x8*)&As[cur^1][arow][aseg*8] = *(bf16x8*)tmp;
        }
        // issue global load for slab step+2
        if(step < 6){
            s0 = *(const float4*)(aSrc + (step+2)*32 + 0);
            s1 = *(const float4*)(aSrc + (step+2)*32 + 4);
        }
        #pragma unroll
        for(int tn = 0; tn < 4; tn++) bcur[tn] = bnext[tn];
        __syncthreads();
    }

    if(role){
        const int b  = brow >> 13;
        const int nb = brow & 8191;
        const size_t blk = tile;
        #pragma unroll
        for(int tn = 0; tn < 4; tn++){
            int col = w*64 + tn*16 + l15;
            int hh = col >> 6, rr = col & 63;
            float bcol = bias[col];
            float rv[16];
            float m16 = -1e30f;
            #pragma unroll
            for(int tm = 0; tm < 4; tm++){
                #pragma unroll
                for(int reg = 0; reg < 4; reg++){
                    float v = acc[tm][tn][reg] + bcol;
                    unsigned short ub = f2bu(v);
                    int n = nb + tm*16 + q*4 + reg;
                    outB[(((size_t)(b*HEAD + hh))*NN + n)*64 + rr] = ub;
                    float vr = u2f(ub);
                    rv[tm*4+reg] = vr;
                    m16 = fmaxf(m16, vr);
                }
            }
            float s16 = 0.f;
            #pragma unroll
            for(int i = 0; i < 16; i++) s16 += __expf(rv[i] - m16);
            // merge across quads (same col on lanes l15, +16, +32, +48)
            #pragma unroll
            for(int off = 16; off <= 32; off <<= 1){
                float m2 = __shfl_xor(m16, off, 64);
                float s2 = __shfl_xor(s16, off, 64);
                float nm = fmaxf(m16, m2);
                s16 = s16*__expf(m16-nm) + s2*__expf(m2-nm);
                m16 = nm;
            }
            if(q == 0){
                Pm[blk*256 + col] = m16;
                Ps[blk*256 + col] = s16;
            }
        }
    } else {
        #pragma unroll
        for(int tn = 0; tn < 4; tn++){
            int col = w*64 + tn*16 + l15;
            float bcol = bias[col];
            #pragma unroll
            for(int tm = 0; tm < 4; tm++){
                #pragma unroll
                for(int reg = 0; reg < 4; reg++){
                    int grow = brow + tm*16 + q*4 + reg;
                    outF[(size_t)grow*256 + col] = acc[tm][tn][reg] + bcol;
                }
            }
        }
    }
}

// ---------------------------------------------------------------------------
// kC: merge per-block stats -> M,S per (b, col). grid 8 x 256.
// ---------------------------------------------------------------------------
__global__ void __launch_bounds__(256) kC(const float* __restrict__ Pm, const float* __restrict__ Ps,
                                          float* __restrict__ M, float* __restrict__ S)
{
    const int b = blockIdx.x, col = threadIdx.x;
    float m = -1e30f;
    for(int c = 0; c < 128; c++)
        m = fmaxf(m, Pm[(size_t)(b*128 + c)*256 + col]);
    float s = 0.f;
    for(int c = 0; c < 128; c++){
        size_t i = (size_t)(b*128 + c)*256 + col;
        s += Ps[i] * __expf(Pm[i] - m);
    }
    M[b*256 + col] = m;
    S[b*256 + col] = s;
}

// ---------------------------------------------------------------------------
// kD: per block (bh, 256-row chunk): thread owns a row; in-register row
//   softmax; LDS-transposed bf16 operands; MFMA pooledT[d][r] += ...
//   (1/rowsum folded into the xv operand). grid (32, 32). LDS 64 KB.
// ---------------------------------------------------------------------------
__global__ void __launch_bounds__(256) kD(const unsigned short* __restrict__ attn,
                                          const float* __restrict__ xv,
                                          float* __restrict__ pooledT)
{
    __shared__ unsigned short s1T[64*256];  // [r][row] swizzled: raw exp(L - rowmax)
    __shared__ unsigned short xvT[64*256];  // [d][row] swizzled: xv / rowsum

    const int t = threadIdx.x, lane = t & 63, w = t >> 6;
    const int bh = blockIdx.x, chunk = blockIdx.y;
    const int b = bh >> 2, h = bh & 3;
    const int n0 = chunk * 256;
    const int row = t;

    // ---- phase 1: row softmax + transposed staging ----
    {
        const uint4* ap = (const uint4*)(attn + ((size_t)bh*NN + n0 + row)*64);
        uint4 ar[8];
        #pragma unroll
        for(int c = 0; c < 8; c++) ar[c] = ap[c];
        float vals[64];
        #pragma unroll
        for(int c = 0; c < 8; c++){
            unsigned int uu[4] = {ar[c].x, ar[c].y, ar[c].z, ar[c].w};
            #pragma unroll
            for(int p = 0; p < 4; p++){
                vals[c*8 + p*2 + 0] = __uint_as_float(uu[p] << 16);
                vals[c*8 + p*2 + 1] = __uint_as_float(uu[p] & 0xffff0000u);
            }
        }
        float mx = -1e30f;
        #pragma unroll
        for(int r = 0; r < 64; r++) mx = fmaxf(mx, vals[r]);
        float s = 0.f;
        #pragma unroll
        for(int r = 0; r < 64; r++){
            float e = __expf(vals[r] - mx);
            s += e;
            s1T[r*256 + swz(row, r)] = f2bu(e);
        }
        float rs = 1.f / s;
        const float4* xp = (const float4*)(xv + ((size_t)(b*NN + n0 + row))*256 + h*64);
        #pragma unroll
        for(int c = 0; c < 16; c++){
            float4 f = xp[c];
            int d0 = c*4;
            xvT[(d0+0)*256 + swz(row, d0+0)] = f2bu(f.x * rs);
            xvT[(d0+1)*256 + swz(row, d0+1)] = f2bu(f.y * rs);
            xvT[(d0+2)*256 + swz(row, d0+2)] = f2bu(f.z * rs);
            xvT[(d0+3)*256 + swz(row, d0+3)] = f2bu(f.w * rs);
        }
    }
    __syncthreads();

    // ---- phase 2: MFMA pooledT[d][r] = sum_row xvT . s1T ----
    const int q = lane >> 4, l15 = lane & 15;
    const int dm = w*16 + l15;   // a-frag outer (d)
    f32x4 acc[4];
    #pragma unroll
    for(int tn = 0; tn < 4; tn++) acc[tn] = (f32x4){0.f,0.f,0.f,0.f};

    #pragma unroll
    for(int slab = 0; slab < 8; slab++){
        int c = slab*4 + q;
        bf16x8 a = *(const bf16x8*)&xvT[dm*256 + ((c ^ (dm & 7))<<3)];
        #pragma unroll
        for(int tn = 0; tn < 4; tn++){
            int rn = tn*16 + l15;
            bf16x8 bb = *(const bf16x8*)&s1T[rn*256 + ((c ^ (rn & 7))<<3)];
            acc[tn] = __builtin_amdgcn_mfma_f32_16x16x32_bf16(a, bb, acc[tn], 0, 0, 0);
        }
    }
    #pragma unroll
    for(int tn = 0; tn < 4; tn++){
        #pragma unroll
        for(int reg = 0; reg < 4; reg++){
            int d = w*16 + q*4 + reg;
            int r = tn*16 + l15;
            atomicAdd(&pooledT[((size_t)bh*64 + d)*64 + r], acc[tn][reg]);
        }
    }
}

// ---------------------------------------------------------------------------
// kE: per block (bh, 256-row chunk): thread owns a row; s2 from M/S (LDS
//   broadcast); MFMA v = s2t @ pooledT; out = sa*xv + sb*v. grid (32, 32).
// ---------------------------------------------------------------------------
__global__ void __launch_bounds__(256) kE(const unsigned short* __restrict__ attn,
                                          const float* __restrict__ xvin,
                                          const float* __restrict__ pooledT,
                                          const float* __restrict__ Mst, const float* __restrict__ Sst,
                                          const float* __restrict__ alpha, const float* __restrict__ beta,
                                          float* __restrict__ out)
{
    __shared__ unsigned short s2t[256*64];  // [row][r] swizzled
    __shared__ unsigned short plT[64*64];   // [d][r] swizzled
    __shared__ float Ms[64], Sinv[64];

    const int t = threadIdx.x, lane = t & 63, w = t >> 6;
    const int bh = blockIdx.x, chunk = blockIdx.y;
    const int b = bh >> 2, h = bh & 3;
    const int n0 = chunk * 256;
    const int row = t;

    if(t < 64){
        Ms[t]   = Mst[b*256 + h*64 + t];
        Sinv[t] = 1.f / Sst[b*256 + h*64 + t];
    }
    // stage pooledT -> bf16 LDS [d][r]
    {
        int d = t >> 2, seg = t & 3;
        const float4* pp = (const float4*)(pooledT + ((size_t)bh*64 + d)*64 + seg*16);
        float4 p0 = pp[0], p1 = pp[1], p2 = pp[2], p3 = pp[3];
        __attribute__((aligned(16))) unsigned short tmp[16] = {
            f2bu(p0.x),f2bu(p0.y),f2bu(p0.z),f2bu(p0.w),
            f2bu(p1.x),f2bu(p1.y),f2bu(p1.z),f2bu(p1.w),
            f2bu(p2.x),f2bu(p2.y),f2bu(p2.z),f2bu(p2.w),
            f2bu(p3.x),f2bu(p3.y),f2bu(p3.z),f2bu(p3.w)};
        int c0 = seg*2;
        *(uint4*)&plT[d*64 + (((c0+0) ^ (d&7))<<3)] = *(uint4*)&tmp[0];
        *(uint4*)&plT[d*64 + (((c0+1) ^ (d&7))<<3)] = *(uint4*)&tmp[8];
    }
    __syncthreads();

    // ---- phase 1: s2 rows ----
    {
        const uint4* ap = (const uint4*)(attn + ((size_t)bh*NN + n0 + row)*64);
        #pragma unroll
        for(int c = 0; c < 8; c++){
            uint4 u = ap[c];
            unsigned int uu[4] = {u.x, u.y, u.z, u.w};
            unsigned int ov[4];
            #pragma unroll
            for(int p = 0; p < 4; p++){
                int r = c*8 + p*2;
                float v0 = __uint_as_float(uu[p] << 16);
                float v1 = __uint_as_float(uu[p] & 0xffff0000u);
                float e0 = __expf(v0 - Ms[r])   * Sinv[r];
                float e1 = __expf(v1 - Ms[r+1]) * Sinv[r+1];
                ov[p] = (unsigned int)f2bu(e0) | ((unsigned int)f2bu(e1) << 16);
            }
            uint4 w4; w4.x = ov[0]; w4.y = ov[1]; w4.z = ov[2]; w4.w = ov[3];
            *(uint4*)&s2t[row*64 + ((c ^ (row&7))<<3)] = w4;
        }
    }
    __syncthreads();

    // ---- phase 2: MFMA v[row][d] = sum_r s2t . plT ----
    const int q = lane >> 4, l15 = lane & 15;
    f32x4 acc[4][4];
    #pragma unroll
    for(int tm = 0; tm < 4; tm++)
        #pragma unroll
        for(int tn = 0; tn < 4; tn++) acc[tm][tn] = (f32x4){0.f,0.f,0.f,0.f};

    #pragma unroll
    for(int s = 0; s < 2; s++){
        int c = s*4 + q;
        bf16x8 bfr[4], af[4];
        #pragma unroll
        for(int tn = 0; tn < 4; tn++){
            int dn = tn*16 + l15;
            bfr[tn] = *(const bf16x8*)&plT[dn*64 + ((c ^ (dn&7))<<3)];
        }
        #pragma unroll
        for(int tm = 0; tm < 4; tm++){
            int ra = w*64 + tm*16 + l15;
            af[tm] = *(const bf16x8*)&s2t[ra*64 + ((c ^ (ra&7))<<3)];
        }
        #pragma unroll
        for(int tm = 0; tm < 4; tm++)
            #pragma unroll
            for(int tn = 0; tn < 4; tn++)
                acc[tm][tn] = __builtin_amdgcn_mfma_f32_16x16x32_bf16(
                    af[tm], bfr[tn], acc[tm][tn], 0, 0, 0);
    }

    const float sa = 1.f / (1.f + __expf(-alpha[h]));
    const float sb = 1.f / (1.f + __expf(-beta[h]));
    #pragma unroll
    for(int tm = 0; tm < 4; tm++){
        #pragma unroll
        for(int reg = 0; reg < 4; reg++){
            int rowo = w*64 + tm*16 + q*4 + reg;
            size_t gbase = ((size_t)(b*NN + n0 + rowo))*256 + h*64;
            #pragma unroll
            for(int tn = 0; tn < 4; tn++){
                int d = tn*16 + l15;
                out[gbase + d] = sa*xvin[gbase + d] + sb*acc[tm][tn][reg];
            }
        }
    }
}

extern "C" void kernel_launch(void* const* d_in, const int* in_sizes, int n_in,
                              void* d_out, int out_size, void* d_ws, size_t ws_size,
                              hipStream_t stream)
{
    (void)in_sizes; (void)n_in; (void)out_size; (void)ws_size;
    const float* x     = (const float*)d_in[0];
    const float* z     = (const float*)d_in[1];
    const float* Wq    = (const float*)d_in[2];
    const float* bq    = (const float*)d_in[3];
    const float* Km    = (const float*)d_in[4];
    const float* Wv    = (const float*)d_in[5];
    const float* bv    = (const float*)d_in[6];
    const float* alpha = (const float*)d_in[7];
    const float* beta  = (const float*)d_in[8];
    float* out = (float*)d_out;

    // xv fp32 lives in d_out: kG writes, kD/kE read, kE overwrites out[i]
    // in the same thread that read xv[i].
    float* xv = out;

    char* ws = (char*)d_ws;
    unsigned short* attn  = (unsigned short*)(ws + 0);         // 33,554,432 B  [b][h][n][r]
    float* pooledT = (float*)(ws + 33554432);                  // 524,288 B    [bh][d][r]
    float* Mst     = (float*)(ws + 34078720);                  // 8,192 B      [b][col]
    float* Sst     = (float*)(ws + 34086912);                  // 8,192 B
    float* Pm      = (float*)(ws + 34095104);                  // 1,048,576 B  [1024][256]
    float* Ps      = (float*)(ws + 35143680);                  // 1,048,576 B
    unsigned short* WattnT = (unsigned short*)(ws + 36192256); // 131,072 B
    unsigned short* WvT    = (unsigned short*)(ws + 36323328); // 131,072 B
    float* battn   = (float*)(ws + 36454400);                  // 1,024 B
                                                               // total: 36,455,424 B

    (void)hipMemsetAsync(pooledT, 0, 524288, stream);
    kW<<<dim3(256), 256, 0, stream>>>(Wq, bq, Km, Wv, WattnT, WvT, battn);
    kG<<<dim3(2*BN/64), 256, 0, stream>>>(x, z, WvT, WattnT, bv, battn, xv, attn, Pm, Ps);
    kC<<<dim3(8), 256, 0, stream>>>(Pm, Ps, Mst, Sst);
    kD<<<dim3(32, 32), 256, 0, stream>>>(attn, xv, pooledT);
    kE<<<dim3(32, 32), 256, 0, stream>>>(attn, xv, pooledT, Mst, Sst, alpha, beta, out);
}

// Round 6
// 289.300 us; speedup vs baseline: 1.1179x; 1.0334x over previous
//
#include <hip/hip_runtime.h>
#include <hip/hip_bf16.h>

typedef __hip_bfloat16 bf16;
typedef __attribute__((ext_vector_type(8))) __bf16 bf16x8;
typedef __attribute__((ext_vector_type(4))) float f32x4;

#define BB 8
#define NN 8192
#define DIM 256
#define HEAD 4
#define HD 64
#define RANK 64
#define BN (BB*NN)

__device__ __forceinline__ float b2f(bf16 v){ return __bfloat162float(v); }
__device__ __forceinline__ bf16 f2b(float v){ return __float2bfloat16(v); }
__device__ __forceinline__ unsigned short f2bu(float f){
    bf16 h = __float2bfloat16(f);
    return *(unsigned short*)&h;
}
__device__ __forceinline__ float u2f(unsigned short u){
    unsigned int x = ((unsigned int)u) << 16; return __uint_as_float(x);
}
__device__ __forceinline__ __bf16 f2bb(float f){
    bf16 h = __float2bfloat16(f);
    return *reinterpret_cast<__bf16*>(&h);
}
// physical position of (outer, k) in a chunk-swizzled [outer][K] bf16 LDS tile
__device__ __forceinline__ int swz(int k, int outer){
    return (((k >> 3) ^ (outer & 7)) << 3) | (k & 7);
}

// ---------------------------------------------------------------------------
// kW: precompute WattnT[c][f] (K folded, /8 folded), WvT[c][f], battn[c].
//     Also zeroes pooledT (replaces the hipMemsetAsync dispatch).
// ---------------------------------------------------------------------------
__global__ void __launch_bounds__(256) kW(
    const float* __restrict__ Wq, const float* __restrict__ bq,
    const float* __restrict__ Km, const float* __restrict__ Wv,
    unsigned short* __restrict__ WattnT, unsigned short* __restrict__ WvT,
    float* __restrict__ battn, float* __restrict__ pooledZ)
{
    const int c = blockIdx.x;       // output col = h*64+r
    const int h = c >> 6, r = c & 63;
    const int t = threadIdx.x;      // f

    // zero pooledT: 131072 floats / 65536 threads = 2 per thread
    {
        int idx = (blockIdx.x*256 + t)*2;
        *(float2*)&pooledZ[idx] = (float2){0.f, 0.f};
    }

    __shared__ float Ks[64];
    if(t < 64) Ks[t] = Km[((size_t)r*HEAD + h)*64 + t];
    __syncthreads();

    const float* wqrow = Wq + (size_t)t*DIM + h*64;
    float a = 0.f;
    #pragma unroll
    for(int d = 0; d < 64; d++) a = fmaf(wqrow[d], Ks[d], a);
    WattnT[(size_t)c*DIM + t] = f2bu(0.125f * a);
    WvT[(size_t)c*DIM + t]    = f2bu(Wv[(size_t)t*DIM + c]);
    if(t == 0){
        float bb = 0.f;
        for(int d = 0; d < 64; d++) bb += bq[h*64+d]*Ks[d];
        battn[c] = 0.125f * bb;
    }
}

// ---------------------------------------------------------------------------
// kG: merged GEMM dispatch, 2048 blocks. role = blockIdx.x & 1:
//   role 0: xv  = x @ WvT^T + bv        -> fp32 outF
//   role 1: attn = z @ WattnT^T + battn -> bf16 attn + col stats Pm/Ps
// Single-barrier structure: the whole 64x256 A tile is staged into LDS
// (8 K-slabs, verified [64][40] per-slab layout) behind ONE __syncthreads();
// the 8-step K-loop then runs barrier-free with W b-fragments prefetched
// 2 steps deep from L2. Waves desync freely -> TLP hides ds_read/L2 latency.
// ---------------------------------------------------------------------------
__global__ void __launch_bounds__(256) kG(
    const float* __restrict__ x, const float* __restrict__ z,
    const unsigned short* __restrict__ WvT, const unsigned short* __restrict__ WattnT,
    const float* __restrict__ bv, const float* __restrict__ battn,
    float* __restrict__ outF, unsigned short* __restrict__ outB,
    float* __restrict__ Pm, float* __restrict__ Ps)
{
    __shared__ __attribute__((aligned(16))) __bf16 As8[8][64][40];  // 40 KB

    const int role = blockIdx.x & 1;
    const int tile = blockIdx.x >> 1;

    const float* A            = role ? z : x;
    const unsigned short* WT  = role ? WattnT : WvT;
    const float* bias         = role ? battn : bv;

    const int t    = threadIdx.x;
    const int lane = t & 63;
    const int w    = t >> 6;
    const int q    = lane >> 4;
    const int l15  = lane & 15;
    const int brow = tile * 64;
    const int arow = t >> 2, aseg = t & 3;

    const float* aSrc = A + (size_t)(brow + arow)*DIM + aseg*8;
    //   b-frag col = w*64 + tn*16 + l15, k = q*8 .. +8   (bf16 in WT)
    const unsigned short* bBase = WT + (size_t)(w*64 + l15)*DIM + q*8;

    // ---- B prefetch depth 2: steps 0 and 1 issued before staging ----
    bf16x8 b0[4], b1[4];
    #pragma unroll
    for(int tn = 0; tn < 4; tn++)
        b0[tn] = *(const bf16x8*)(bBase + (size_t)tn*16*DIM);
    #pragma unroll
    for(int tn = 0; tn < 4; tn++)
        b1[tn] = *(const bf16x8*)(bBase + (size_t)tn*16*DIM + 32);

    // ---- stage the whole A tile: 8 slabs, 2 float4 loads each ----
    #pragma unroll
    for(int s = 0; s < 8; s++){
        float4 v0 = *(const float4*)(aSrc + s*32);
        float4 v1 = *(const float4*)(aSrc + s*32 + 4);
        __attribute__((aligned(16))) __bf16 tmp[8] = {
            f2bb(v0.x), f2bb(v0.y), f2bb(v0.z), f2bb(v0.w),
            f2bb(v1.x), f2bb(v1.y), f2bb(v1.z), f2bb(v1.w)};
        *(bf16x8*)&As8[s][arow][aseg*8] = *(bf16x8*)tmp;
    }

    f32x4 acc[4][4];
    #pragma unroll
    for(int tm = 0; tm < 4; tm++)
        #pragma unroll
        for(int tn = 0; tn < 4; tn++) acc[tm][tn] = (f32x4){0.f,0.f,0.f,0.f};

    __syncthreads();   // the ONLY barrier

    #pragma unroll
    for(int step = 0; step < 8; step++){
        // prefetch W fragments 2 steps ahead (L2-resident)
        bf16x8 b2[4];
        if(step < 6){
            #pragma unroll
            for(int tn = 0; tn < 4; tn++)
                b2[tn] = *(const bf16x8*)(bBase + (size_t)tn*16*DIM + (step+2)*32);
        }

        bf16x8 af[4];
        #pragma unroll
        for(int tm = 0; tm < 4; tm++)
            af[tm] = *(const bf16x8*)&As8[step][tm*16 + l15][q*8];

        #pragma unroll
        for(int tm = 0; tm < 4; tm++)
            #pragma unroll
            for(int tn = 0; tn < 4; tn++)
                acc[tm][tn] = __builtin_amdgcn_mfma_f32_16x16x32_bf16(
                    af[tm], b0[tn], acc[tm][tn], 0, 0, 0);

        #pragma unroll
        for(int tn = 0; tn < 4; tn++){ b0[tn] = b1[tn]; b1[tn] = b2[tn]; }
    }

    if(role){
        const int b  = brow >> 13;
        const int nb = brow & 8191;
        const size_t blk = tile;
        #pragma unroll
        for(int tn = 0; tn < 4; tn++){
            int col = w*64 + tn*16 + l15;
            int hh = col >> 6, rr = col & 63;
            float bcol = bias[col];
            float rv[16];
            float m16 = -1e30f;
            #pragma unroll
            for(int tm = 0; tm < 4; tm++){
                #pragma unroll
                for(int reg = 0; reg < 4; reg++){
                    float v = acc[tm][tn][reg] + bcol;
                    unsigned short ub = f2bu(v);
                    int n = nb + tm*16 + q*4 + reg;
                    outB[(((size_t)(b*HEAD + hh))*NN + n)*64 + rr] = ub;
                    float vr = u2f(ub);
                    rv[tm*4+reg] = vr;
                    m16 = fmaxf(m16, vr);
                }
            }
            float s16 = 0.f;
            #pragma unroll
            for(int i = 0; i < 16; i++) s16 += __expf(rv[i] - m16);
            // merge across quads (same col on lanes l15, +16, +32, +48)
            #pragma unroll
            for(int off = 16; off <= 32; off <<= 1){
                float m2 = __shfl_xor(m16, off, 64);
                float s2 = __shfl_xor(s16, off, 64);
                float nm = fmaxf(m16, m2);
                s16 = s16*__expf(m16-nm) + s2*__expf(m2-nm);
                m16 = nm;
            }
            if(q == 0){
                Pm[blk*256 + col] = m16;
                Ps[blk*256 + col] = s16;
            }
        }
    } else {
        #pragma unroll
        for(int tn = 0; tn < 4; tn++){
            int col = w*64 + tn*16 + l15;
            float bcol = bias[col];
            #pragma unroll
            for(int tm = 0; tm < 4; tm++){
                #pragma unroll
                for(int reg = 0; reg < 4; reg++){
                    int grow = brow + tm*16 + q*4 + reg;
                    outF[(size_t)grow*256 + col] = acc[tm][tn][reg] + bcol;
                }
            }
        }
    }
}

// ---------------------------------------------------------------------------
// kD: per block (bh, 256-row chunk): thread owns a row; in-register row
//   softmax; LDS-transposed bf16 operands; MFMA pooledT[d][r] += ...
//   (1/rowsum folded into the xv operand). grid (32, 32). LDS 64 KB.
//   Blocks with chunk==0 && (bh&3)==0 also perform the old kC stat-merge
//   (Pm/Ps -> Mst/Sst); kE (next dispatch) is the only consumer.
// ---------------------------------------------------------------------------
__global__ void __launch_bounds__(256) kD(const unsigned short* __restrict__ attn,
                                          const float* __restrict__ xv,
                                          float* __restrict__ pooledT,
                                          const float* __restrict__ Pm, const float* __restrict__ Ps,
                                          float* __restrict__ Mst, float* __restrict__ Sst)
{
    __shared__ unsigned short s1T[64*256];  // [r][row] swizzled: raw exp(L - rowmax)
    __shared__ unsigned short xvT[64*256];  // [d][row] swizzled: xv / rowsum

    const int t = threadIdx.x, lane = t & 63, w = t >> 6;
    const int bh = blockIdx.x, chunk = blockIdx.y;
    const int b = bh >> 2, h = bh & 3;
    const int n0 = chunk * 256;
    const int row = t;

    // ---- folded kC: 8 designated blocks merge per-block stats ----
    if(chunk == 0 && (bh & 3) == 0){
        const int bb = bh >> 2, col = t;
        float m = -1e30f;
        for(int c = 0; c < 128; c++)
            m = fmaxf(m, Pm[(size_t)(bb*128 + c)*256 + col]);
        float s = 0.f;
        for(int c = 0; c < 128; c++){
            size_t i = (size_t)(bb*128 + c)*256 + col;
            s += Ps[i] * __expf(Pm[i] - m);
        }
        Mst[bb*256 + col] = m;
        Sst[bb*256 + col] = s;
    }

    // ---- phase 1: row softmax + transposed staging ----
    {
        const uint4* ap = (const uint4*)(attn + ((size_t)bh*NN + n0 + row)*64);
        uint4 ar[8];
        #pragma unroll
        for(int c = 0; c < 8; c++) ar[c] = ap[c];
        float vals[64];
        #pragma unroll
        for(int c = 0; c < 8; c++){
            unsigned int uu[4] = {ar[c].x, ar[c].y, ar[c].z, ar[c].w};
            #pragma unroll
            for(int p = 0; p < 4; p++){
                vals[c*8 + p*2 + 0] = __uint_as_float(uu[p] << 16);
                vals[c*8 + p*2 + 1] = __uint_as_float(uu[p] & 0xffff0000u);
            }
        }
        float mx = -1e30f;
        #pragma unroll
        for(int r = 0; r < 64; r++) mx = fmaxf(mx, vals[r]);
        float s = 0.f;
        #pragma unroll
        for(int r = 0; r < 64; r++){
            float e = __expf(vals[r] - mx);
            s += e;
            s1T[r*256 + swz(row, r)] = f2bu(e);
        }
        float rs = 1.f / s;
        const float4* xp = (const float4*)(xv + ((size_t)(b*NN + n0 + row))*256 + h*64);
        #pragma unroll
        for(int c = 0; c < 16; c++){
            float4 f = xp[c];
            int d0 = c*4;
            xvT[(d0+0)*256 + swz(row, d0+0)] = f2bu(f.x * rs);
            xvT[(d0+1)*256 + swz(row, d0+1)] = f2bu(f.y * rs);
            xvT[(d0+2)*256 + swz(row, d0+2)] = f2bu(f.z * rs);
            xvT[(d0+3)*256 + swz(row, d0+3)] = f2bu(f.w * rs);
        }
    }
    __syncthreads();

    // ---- phase 2: MFMA pooledT[d][r] = sum_row xvT . s1T ----
    const int q = lane >> 4, l15 = lane & 15;
    const int dm = w*16 + l15;   // a-frag outer (d)
    f32x4 acc[4];
    #pragma unroll
    for(int tn = 0; tn < 4; tn++) acc[tn] = (f32x4){0.f,0.f,0.f,0.f};

    #pragma unroll
    for(int slab = 0; slab < 8; slab++){
        int c = slab*4 + q;
        bf16x8 a = *(const bf16x8*)&xvT[dm*256 + ((c ^ (dm & 7))<<3)];
        #pragma unroll
        for(int tn = 0; tn < 4; tn++){
            int rn = tn*16 + l15;
            bf16x8 bb = *(const bf16x8*)&s1T[rn*256 + ((c ^ (rn & 7))<<3)];
            acc[tn] = __builtin_amdgcn_mfma_f32_16x16x32_bf16(a, bb, acc[tn], 0, 0, 0);
        }
    }
    #pragma unroll
    for(int tn = 0; tn < 4; tn++){
        #pragma unroll
        for(int reg = 0; reg < 4; reg++){
            int d = w*16 + q*4 + reg;
            int r = tn*16 + l15;
            atomicAdd(&pooledT[((size_t)bh*64 + d)*64 + r], acc[tn][reg]);
        }
    }
}

// ---------------------------------------------------------------------------
// kE: per block (bh, 256-row chunk): thread owns a row; s2 from M/S (LDS
//   broadcast); MFMA v = s2t @ pooledT; out = sa*xv + sb*v. grid (32, 32).
// ---------------------------------------------------------------------------
__global__ void __launch_bounds__(256) kE(const unsigned short* __restrict__ attn,
                                          const float* __restrict__ xvin,
                                          const float* __restrict__ pooledT,
                                          const float* __restrict__ Mst, const float* __restrict__ Sst,
                                          const float* __restrict__ alpha, const float* __restrict__ beta,
                                          float* __restrict__ out)
{
    __shared__ unsigned short s2t[256*64];  // [row][r] swizzled
    __shared__ unsigned short plT[64*64];   // [d][r] swizzled
    __shared__ float Ms[64], Sinv[64];

    const int t = threadIdx.x, lane = t & 63, w = t >> 6;
    const int bh = blockIdx.x, chunk = blockIdx.y;
    const int b = bh >> 2, h = bh & 3;
    const int n0 = chunk * 256;
    const int row = t;

    if(t < 64){
        Ms[t]   = Mst[b*256 + h*64 + t];
        Sinv[t] = 1.f / Sst[b*256 + h*64 + t];
    }
    // stage pooledT -> bf16 LDS [d][r]
    {
        int d = t >> 2, seg = t & 3;
        const float4* pp = (const float4*)(pooledT + ((size_t)bh*64 + d)*64 + seg*16);
        float4 p0 = pp[0], p1 = pp[1], p2 = pp[2], p3 = pp[3];
        __attribute__((aligned(16))) unsigned short tmp[16] = {
            f2bu(p0.x),f2bu(p0.y),f2bu(p0.z),f2bu(p0.w),
            f2bu(p1.x),f2bu(p1.y),f2bu(p1.z),f2bu(p1.w),
            f2bu(p2.x),f2bu(p2.y),f2bu(p2.z),f2bu(p2.w),
            f2bu(p3.x),f2bu(p3.y),f2bu(p3.z),f2bu(p3.w)};
        int c0 = seg*2;
        *(uint4*)&plT[d*64 + (((c0+0) ^ (d&7))<<3)] = *(uint4*)&tmp[0];
        *(uint4*)&plT[d*64 + (((c0+1) ^ (d&7))<<3)] = *(uint4*)&tmp[8];
    }
    __syncthreads();

    // ---- phase 1: s2 rows ----
    {
        const uint4* ap = (const uint4*)(attn + ((size_t)bh*NN + n0 + row)*64);
        #pragma unroll
        for(int c = 0; c < 8; c++){
            uint4 u = ap[c];
            unsigned int uu[4] = {u.x, u.y, u.z, u.w};
            unsigned int ov[4];
            #pragma unroll
            for(int p = 0; p < 4; p++){
                int r = c*8 + p*2;
                float v0 = __uint_as_float(uu[p] << 16);
                float v1 = __uint_as_float(uu[p] & 0xffff0000u);
                float e0 = __expf(v0 - Ms[r])   * Sinv[r];
                float e1 = __expf(v1 - Ms[r+1]) * Sinv[r+1];
                ov[p] = (unsigned int)f2bu(e0) | ((unsigned int)f2bu(e1) << 16);
            }
            uint4 w4; w4.x = ov[0]; w4.y = ov[1]; w4.z = ov[2]; w4.w = ov[3];
            *(uint4*)&s2t[row*64 + ((c ^ (row&7))<<3)] = w4;
        }
    }
    __syncthreads();

    // ---- phase 2: MFMA v[row][d] = sum_r s2t . plT ----
    const int q = lane >> 4, l15 = lane & 15;
    f32x4 acc[4][4];
    #pragma unroll
    for(int tm = 0; tm < 4; tm++)
        #pragma unroll
        for(int tn = 0; tn < 4; tn++) acc[tm][tn] = (f32x4){0.f,0.f,0.f,0.f};

    #pragma unroll
    for(int s = 0; s < 2; s++){
        int c = s*4 + q;
        bf16x8 bfr[4], af[4];
        #pragma unroll
        for(int tn = 0; tn < 4; tn++){
            int dn = tn*16 + l15;
            bfr[tn] = *(const bf16x8*)&plT[dn*64 + ((c ^ (dn&7))<<3)];
        }
        #pragma unroll
        for(int tm = 0; tm < 4; tm++){
            int ra = w*64 + tm*16 + l15;
            af[tm] = *(const bf16x8*)&s2t[ra*64 + ((c ^ (ra&7))<<3)];
        }
        #pragma unroll
        for(int tm = 0; tm < 4; tm++)
            #pragma unroll
            for(int tn = 0; tn < 4; tn++)
                acc[tm][tn] = __builtin_amdgcn_mfma_f32_16x16x32_bf16(
                    af[tm], bfr[tn], acc[tm][tn], 0, 0, 0);
    }

    const float sa = 1.f / (1.f + __expf(-alpha[h]));
    const float sb = 1.f / (1.f + __expf(-beta[h]));
    #pragma unroll
    for(int tm = 0; tm < 4; tm++){
        #pragma unroll
        for(int reg = 0; reg < 4; reg++){
            int rowo = w*64 + tm*16 + q*4 + reg;
            size_t gbase = ((size_t)(b*NN + n0 + rowo))*256 + h*64;
            #pragma unroll
            for(int tn = 0; tn < 4; tn++){
                int d = tn*16 + l15;
                out[gbase + d] = sa*xvin[gbase + d] + sb*acc[tm][tn][reg];
            }
        }
    }
}

extern "C" void kernel_launch(void* const* d_in, const int* in_sizes, int n_in,
                              void* d_out, int out_size, void* d_ws, size_t ws_size,
                              hipStream_t stream)
{
    (void)in_sizes; (void)n_in; (void)out_size; (void)ws_size;
    const float* x     = (const float*)d_in[0];
    const float* z     = (const float*)d_in[1];
    const float* Wq    = (const float*)d_in[2];
    const float* bq    = (const float*)d_in[3];
    const float* Km    = (const float*)d_in[4];
    const float* Wv    = (const float*)d_in[5];
    const float* bv    = (const float*)d_in[6];
    const float* alpha = (const float*)d_in[7];
    const float* beta  = (const float*)d_in[8];
    float* out = (float*)d_out;

    // xv fp32 lives in d_out: kG writes, kD/kE read, kE overwrites out[i]
    // in the same thread that read xv[i].
    float* xv = out;

    char* ws = (char*)d_ws;
    unsigned short* attn  = (unsigned short*)(ws + 0);         // 33,554,432 B  [b][h][n][r]
    float* pooledT = (float*)(ws + 33554432);                  // 524,288 B    [bh][d][r]
    float* Mst     = (float*)(ws + 34078720);                  // 8,192 B      [b][col]
    float* Sst     = (float*)(ws + 34086912);                  // 8,192 B
    float* Pm      = (float*)(ws + 34095104);                  // 1,048,576 B  [1024][256]
    float* Ps      = (float*)(ws + 35143680);                  // 1,048,576 B
    unsigned short* WattnT = (unsigned short*)(ws + 36192256); // 131,072 B
    unsigned short* WvT    = (unsigned short*)(ws + 36323328); // 131,072 B
    float* battn   = (float*)(ws + 36454400);                  // 1,024 B
                                                               // total: 36,455,424 B

    kW<<<dim3(256), 256, 0, stream>>>(Wq, bq, Km, Wv, WattnT, WvT, battn, pooledT);
    kG<<<dim3(2*BN/64), 256, 0, stream>>>(x, z, WvT, WattnT, bv, battn, xv, attn, Pm, Ps);
    kD<<<dim3(32, 32), 256, 0, stream>>>(attn, xv, pooledT, Pm, Ps, Mst, Sst);
    kE<<<dim3(32, 32), 256, 0, stream>>>(attn, xv, pooledT, Mst, Sst, alpha, beta, out);
}